// Round 2
// 232.734 us; speedup vs baseline: 1.0056x; 1.0056x over previous
//
#include <hip/hip_runtime.h>

// LIF spiking recurrence over T=8:
//   mem = mem*TAU + x[t]*alpha; spike = (mem > Vth); mem = spike ? 0 : mem
// One thread per float4 (4 spatial positions).
//
// R10: R9's counted-vmcnt pipeline + store-data-hazard fix.
// R9 failed (absmax 3.27): asm stores hid the VMEM store-data hazard from
// the compiler — sp's registers were reused for step t+1's mem/temps while
// store t was still in flight (store data VGPRs must stay intact until
// vmcnt retires the store). Fix: distinct sp0..sp7, all pinned live to the
// end of the kernel by an empty asm, so no store's data registers are ever
// reused. Pipeline logic unchanged from R9:
//   order (all volatile asm, program order guaranteed):
//     L0..L7, then per step t: s_waitcnt vmcnt(7); compute; store t
//   at wait t: issued = 8 loads + t stores; vmcnt(7) => >= t+1 retired
//   in order => load t complete; never blocks on a store (even t=7 only
//   requires the 8 loads retired). Store t issues as soon as load t lands,
//   overlapping the write stream with the remaining loads' HBM latency
//   instead of R8's full vmcnt(0) drain + store burst.

#define TAU 0.5f
#define T_STEPS 8

typedef float vf4 __attribute__((ext_vector_type(4)));

__global__ __launch_bounds__(256) void lif_kernel(
    const float* __restrict__ x,
    const float* __restrict__ alpha_p,
    const float* __restrict__ vth_p,
    float* __restrict__ out,
    int n4)  // float4 groups per timestep
{
    const int i = blockIdx.x * blockDim.x + threadIdx.x;
    if (i >= n4) return;

    const float alpha = alpha_p[0];
    const float vth   = vth_p[0];

    const vf4* __restrict__ x4   = (const vf4*)x;
    vf4* __restrict__       out4 = (vf4*)out;

    vf4 xt0, xt1, xt2, xt3, xt4, xt5, xt6, xt7;

    const vf4* p0 = x4 + (size_t)0 * n4 + i;
    const vf4* p1 = x4 + (size_t)1 * n4 + i;
    const vf4* p2 = x4 + (size_t)2 * n4 + i;
    const vf4* p3 = x4 + (size_t)3 * n4 + i;
    const vf4* p4 = x4 + (size_t)4 * n4 + i;
    const vf4* p5 = x4 + (size_t)5 * n4 + i;
    const vf4* p6 = x4 + (size_t)6 * n4 + i;
    const vf4* p7 = x4 + (size_t)7 * n4 + i;

    // 8 nontemporal loads issued back-to-back: streaming cache policy
    // (no L2/L3 allocation) + guaranteed 8 outstanding per wave.
    asm volatile("global_load_dwordx4 %0, %1, off nt" : "=v"(xt0) : "v"(p0));
    asm volatile("global_load_dwordx4 %0, %1, off nt" : "=v"(xt1) : "v"(p1));
    asm volatile("global_load_dwordx4 %0, %1, off nt" : "=v"(xt2) : "v"(p2));
    asm volatile("global_load_dwordx4 %0, %1, off nt" : "=v"(xt3) : "v"(p3));
    asm volatile("global_load_dwordx4 %0, %1, off nt" : "=v"(xt4) : "v"(p4));
    asm volatile("global_load_dwordx4 %0, %1, off nt" : "=v"(xt5) : "v"(p5));
    asm volatile("global_load_dwordx4 %0, %1, off nt" : "=v"(xt6) : "v"(p6));
    asm volatile("global_load_dwordx4 %0, %1, off nt" : "=v"(xt7) : "v"(p7));

    vf4 mem = (vf4)(0.f);
    // One spike register set per step: store-data registers must stay
    // intact until their store retires (pinned live at kernel end below).
    vf4 sp0, sp1, sp2, sp3, sp4, sp5, sp6, sp7;

#define LIF_STEP(XT, SP, T)                               \
    do {                                                  \
        asm volatile("s_waitcnt vmcnt(7)" : "+v"(XT));    \
        mem = mem * TAU + (XT) * alpha;                   \
        SP.x = (mem.x > vth) ? 1.f : 0.f;                 \
        SP.y = (mem.y > vth) ? 1.f : 0.f;                 \
        SP.z = (mem.z > vth) ? 1.f : 0.f;                 \
        SP.w = (mem.w > vth) ? 1.f : 0.f;                 \
        mem.x = (SP.x > 0.f) ? 0.f : mem.x;               \
        mem.y = (SP.y > 0.f) ? 0.f : mem.y;               \
        mem.z = (SP.z > 0.f) ? 0.f : mem.z;               \
        mem.w = (SP.w > 0.f) ? 0.f : mem.w;               \
        {                                                 \
            vf4* q = out4 + (size_t)(T) * n4 + i;         \
            asm volatile(                                 \
                "global_store_dwordx4 %0, %1, off nt"     \
                :: "v"(q), "v"(SP));                      \
        }                                                 \
    } while (0)

    LIF_STEP(xt0, sp0, 0);
    LIF_STEP(xt1, sp1, 1);
    LIF_STEP(xt2, sp2, 2);
    LIF_STEP(xt3, sp3, 3);
    LIF_STEP(xt4, sp4, 4);
    LIF_STEP(xt5, sp5, 5);
    LIF_STEP(xt6, sp6, 6);
    LIF_STEP(xt7, sp7, 7);
#undef LIF_STEP

    // Pin every store's data registers live until endpgm so the register
    // allocator can never recycle them while a store is in flight.
    asm volatile(""
                 :: "v"(sp0), "v"(sp1), "v"(sp2), "v"(sp3),
                    "v"(sp4), "v"(sp5), "v"(sp6), "v"(sp7));
    // stores drain at s_endpgm (HW holds VGPRs until store data is read)
}

extern "C" void kernel_launch(void* const* d_in, const int* in_sizes, int n_in,
                              void* d_out, int out_size, void* d_ws, size_t ws_size,
                              hipStream_t stream) {
    const float* x     = (const float*)d_in[0];
    const float* alpha = (const float*)d_in[1];
    const float* vth   = (const float*)d_in[2];
    float* out         = (float*)d_out;

    const int total = in_sizes[0];          // T * B * C * H * W
    const int n     = total / T_STEPS;      // spatial elements per timestep
    const int n4    = n / 4;                // float4 groups per timestep

    const int block = 256;
    const int grid  = (n4 + block - 1) / block;
    lif_kernel<<<grid, block, 0, stream>>>(x, alpha, vth, out, n4);
}

// Round 3
// 232.354 us; speedup vs baseline: 1.0072x; 1.0016x over previous
//
#include <hip/hip_runtime.h>

// LIF spiking recurrence over T=8:
//   mem = mem*TAU + x[t]*alpha; spike = (mem > Vth); mem = spike ? 0 : mem
// One thread per float4 (4 spatial positions).
//
// R11: nt loads + CACHEABLE stores (the one policy combo never tested).
// Evidence so far: cacheable loads+stores = 86-101us; nt loads+stores = 74us
// (R3/R8); counted-vmcnt pipeline = neutral (R10 == R8) => throughput wall,
// not latency. Kernel ~72us = 3.7 TB/s vs 6.3 TB/s mixed-copy ceiling.
// Theory: reads are single-use -> keep them nt (no L2/L3 allocation, no
// thrash). Writes are 134 MB -> fit the 256 MB Infinity Cache entirely.
// With reads not competing for lines, cacheable stores retire at cache
// latency and dirty writeback is deferred/overlapped (partly past kernel
// end). Timed kernel becomes read-stream-bound: predict ~45-55us.
// Loads via __builtin_nontemporal_load (compiler handles hazards/waits,
// still emits "nt"); stores plain C++ (cacheable) — no manual vmcnt
// bookkeeping anywhere.

#define TAU 0.5f
#define T_STEPS 8

typedef float vf4 __attribute__((ext_vector_type(4)));

__global__ __launch_bounds__(256) void lif_kernel(
    const float* __restrict__ x,
    const float* __restrict__ alpha_p,
    const float* __restrict__ vth_p,
    float* __restrict__ out,
    int n4)  // float4 groups per timestep
{
    const int i = blockIdx.x * blockDim.x + threadIdx.x;
    if (i >= n4) return;

    const float alpha = alpha_p[0];
    const float vth   = vth_p[0];

    const vf4* __restrict__ x4   = (const vf4*)x;
    vf4* __restrict__       out4 = (vf4*)out;

    // 8 nontemporal loads (streaming policy, no L2/L3 allocation).
    // Builtin form: compiler tracks the data hazard and schedules waits,
    // and will batch these back-to-back on its own (verified in R1-R8 asm).
    vf4 xt0 = __builtin_nontemporal_load(x4 + (size_t)0 * n4 + i);
    vf4 xt1 = __builtin_nontemporal_load(x4 + (size_t)1 * n4 + i);
    vf4 xt2 = __builtin_nontemporal_load(x4 + (size_t)2 * n4 + i);
    vf4 xt3 = __builtin_nontemporal_load(x4 + (size_t)3 * n4 + i);
    vf4 xt4 = __builtin_nontemporal_load(x4 + (size_t)4 * n4 + i);
    vf4 xt5 = __builtin_nontemporal_load(x4 + (size_t)5 * n4 + i);
    vf4 xt6 = __builtin_nontemporal_load(x4 + (size_t)6 * n4 + i);
    vf4 xt7 = __builtin_nontemporal_load(x4 + (size_t)7 * n4 + i);

    vf4 mem = (vf4)(0.f);
    vf4 sp;

#define LIF_STEP(XT, T)                                   \
    do {                                                  \
        mem = mem * TAU + (XT) * alpha;                   \
        sp.x = (mem.x > vth) ? 1.f : 0.f;                 \
        sp.y = (mem.y > vth) ? 1.f : 0.f;                 \
        sp.z = (mem.z > vth) ? 1.f : 0.f;                 \
        sp.w = (mem.w > vth) ? 1.f : 0.f;                 \
        mem.x = (sp.x > 0.f) ? 0.f : mem.x;               \
        mem.y = (sp.y > 0.f) ? 0.f : mem.y;               \
        mem.z = (sp.z > 0.f) ? 0.f : mem.z;               \
        mem.w = (sp.w > 0.f) ? 0.f : mem.w;               \
        out4[(size_t)(T) * n4 + i] = sp;   /* cacheable store */ \
    } while (0)

    LIF_STEP(xt0, 0);
    LIF_STEP(xt1, 1);
    LIF_STEP(xt2, 2);
    LIF_STEP(xt3, 3);
    LIF_STEP(xt4, 4);
    LIF_STEP(xt5, 5);
    LIF_STEP(xt6, 6);
    LIF_STEP(xt7, 7);
#undef LIF_STEP
}

extern "C" void kernel_launch(void* const* d_in, const int* in_sizes, int n_in,
                              void* d_out, int out_size, void* d_ws, size_t ws_size,
                              hipStream_t stream) {
    const float* x     = (const float*)d_in[0];
    const float* alpha = (const float*)d_in[1];
    const float* vth   = (const float*)d_in[2];
    float* out         = (float*)d_out;

    const int total = in_sizes[0];          // T * B * C * H * W
    const int n     = total / T_STEPS;      // spatial elements per timestep
    const int n4    = n / 4;                // float4 groups per timestep

    const int block = 256;
    const int grid  = (n4 + block - 1) / block;
    lif_kernel<<<grid, block, 0, stream>>>(x, alpha, vth, out, n4);
}